// Round 3
// baseline (14919.844 us; speedup 1.0000x reference)
//
#include <hip/hip_runtime.h>
#include <hip/hip_bf16.h>

using bf16 = __hip_bfloat16;

static constexpr int NN = 100000;   // nodes
static constexpr int NE = 1600000;  // message edges
static constexpr int NS = 500000;   // scored edges
static constexpr int HH = 64;       // hidden

__device__ __forceinline__ float b2f(bf16 v) { return __bfloat162float(v); }
__device__ __forceinline__ bf16  f2b(float v) { return __float2bfloat16(v); }

// h = x @ Wn + bn   (NF=2), f32
__global__ void encode_nodes_k(const float* __restrict__ x, const float* __restrict__ Wn,
                               const float* __restrict__ bn, float* __restrict__ h) {
    int tid = blockIdx.x * blockDim.x + threadIdx.x;
    if (tid >= NN * HH) return;
    int r = tid >> 6, j = tid & 63;
    h[tid] = fmaf(x[2 * r], Wn[j], fmaf(x[2 * r + 1], Wn[HH + j], bn[j]));
}

// Fold encoder into layer-0 C:  We0[i][j] = sum_k We[i][k]*C0[k][j];
// bb0[j] = sum_k be[k]*C0[k][j] + cb0[j].  One block of 64 threads.
__global__ void prep_k(const float* __restrict__ We, const float* __restrict__ be,
                       const float* __restrict__ C0, const float* __restrict__ cb0,
                       float* __restrict__ We0, float* __restrict__ bb0) {
    int j = threadIdx.x;
    if (j >= HH) return;
    float s0 = 0.f, s1 = 0.f, sb = 0.f;
    for (int k = 0; k < HH; ++k) {
        float c = C0[k * HH + j];
        s0 = fmaf(We[k], c, s0);
        s1 = fmaf(We[HH + k], c, s1);
        sb = fmaf(be[k], c, sb);
    }
    We0[j] = s0; We0[HH + j] = s1; bb0[j] = sb + cb0[j];
}

// out = h @ W, stored bf16; one matrix per blockIdx.y; wave per row, W-col in VGPRs
__global__ void node_transform_k(const float* __restrict__ h, const float* __restrict__ A,
                                 const float* __restrict__ B, const float* __restrict__ V,
                                 bf16* __restrict__ oA, bf16* __restrict__ oB,
                                 bf16* __restrict__ oV) {
    int lane = threadIdx.x & 63;
    const float* W; bf16* out;
    if (blockIdx.y == 0)      { W = A; out = oA; }
    else if (blockIdx.y == 1) { W = B; out = oB; }
    else                      { W = V; out = oV; }
    float col[HH];
#pragma unroll
    for (int k = 0; k < HH; ++k) col[k] = W[k * HH + lane];
    int wave = blockIdx.x * (blockDim.x >> 6) + (threadIdx.x >> 6);
    int nw = gridDim.x * (blockDim.x >> 6);
    for (int r = wave; r < NN; r += nw) {
        const float* hr = h + (size_t)r * HH;
        float acc = 0.f;
#pragma unroll
        for (int k = 0; k < HH; ++k) acc = fmaf(hr[k], col[k], acc);
        out[(size_t)r * HH + lane] = f2b(acc);
    }
}

// Edge pass for layer LAYER: recompute e_hat chain from e0 + node tables.
// hAB layout: [A0,B0,A1,B1,A2,B2], each [NN*64] bf16.
template <int LAYER>
__global__ void edge_chain_k(const float* __restrict__ e0,
                             const bf16* __restrict__ hAB, const bf16* __restrict__ hV,
                             const float* __restrict__ We0, const float* __restrict__ bb0,
                             const float* __restrict__ cb, const float* __restrict__ C,
                             const int* __restrict__ src, const int* __restrict__ dst,
                             float* __restrict__ num, float* __restrict__ den) {
    int lane = threadIdx.x & 63;
    float c1[HH], c2[HH];
    if constexpr (LAYER >= 1) {
#pragma unroll
        for (int k = 0; k < HH; ++k) c1[k] = C[1 * HH * HH + k * HH + lane];
    }
    if constexpr (LAYER >= 2) {
#pragma unroll
        for (int k = 0; k < HH; ++k) c2[k] = C[2 * HH * HH + k * HH + lane];
    }
    float w0 = We0[lane], w1 = We0[HH + lane], b0 = bb0[lane];
    float cb1 = (LAYER >= 1) ? cb[HH + lane] : 0.f;
    float cb2 = (LAYER >= 2) ? cb[2 * HH + lane] : 0.f;
    const size_t nb = (size_t)NN * HH;

    int wave = blockIdx.x * (blockDim.x >> 6) + (threadIdx.x >> 6);
    int nw = gridDim.x * (blockDim.x >> 6);
    for (int e = wave; e < NE; e += nw) {
        int s = src[e], d = dst[e];
        size_t so = (size_t)s * HH + lane, dofs = (size_t)d * HH + lane;
        float z = fmaf(e0[2 * e], w0, fmaf(e0[2 * e + 1], w1, b0));
        z += b2f(hAB[so]) + b2f(hAB[nb + dofs]);
        if constexpr (LAYER >= 1) {
            float e1 = fmaxf(z, 0.f);
            float acc = cb1 + b2f(hAB[2 * nb + so]) + b2f(hAB[3 * nb + dofs]);
#pragma unroll
            for (int k = 0; k < HH; ++k) acc = fmaf(__shfl(e1, k), c1[k], acc);
            z = acc;
        }
        if constexpr (LAYER >= 2) {
            float e2 = fmaxf(z, 0.f);
            float acc = cb2 + b2f(hAB[4 * nb + so]) + b2f(hAB[5 * nb + dofs]);
#pragma unroll
            for (int k = 0; k < HH; ++k) acc = fmaf(__shfl(e2, k), c2[k], acc);
            z = acc;
        }
        float sig = 1.f / (1.f + __expf(-z));
        atomicAdd(&num[dofs], sig * b2f(hV[so]));
        atomicAdd(&den[dofs], sig);
    }
}

// h = relu(h@U + num/(den+1e-6)) in place
__global__ void node_update_k(float* __restrict__ h, const float* __restrict__ U,
                              const float* __restrict__ num, const float* __restrict__ den) {
    int lane = threadIdx.x & 63;
    float col[HH];
#pragma unroll
    for (int k = 0; k < HH; ++k) col[k] = U[k * HH + lane];
    int wave = blockIdx.x * (blockDim.x >> 6) + (threadIdx.x >> 6);
    int nw = gridDim.x * (blockDim.x >> 6);
    for (int r = wave; r < NN; r += nw) {
        const float* hr = h + (size_t)r * HH;
        float acc = 0.f;
#pragma unroll
        for (int k = 0; k < HH; ++k) acc = fmaf(hr[k], col[k], acc);
        size_t o = (size_t)r * HH + lane;
        h[o] = fmaxf(acc + num[o] / (den[o] + 1e-6f), 0.f);
    }
}

__global__ void zero_k(float4* __restrict__ p, int n4) {
    int i = blockIdx.x * blockDim.x + threadIdx.x;
    int st = gridDim.x * blockDim.x;
    float4 z = make_float4(0.f, 0.f, 0.f, 0.f);
    for (; i < n4; i += st) p[i] = z;
}

// scores = [h[src_s] ; h[dst_s]] @ Wp + bp ; wave per scored edge
__global__ void score_k(const float* __restrict__ h, const float* __restrict__ Wp,
                        const float* __restrict__ bp, const int* __restrict__ ss,
                        const int* __restrict__ ds, float* __restrict__ out) {
    int lane = threadIdx.x & 63;
    int wave = (blockIdx.x * blockDim.x + threadIdx.x) >> 6;
    if (wave >= NS) return;
    int s = ss[wave], d = ds[wave];
    float v = fmaf(h[(size_t)s * HH + lane], Wp[lane],
                   h[(size_t)d * HH + lane] * Wp[HH + lane]);
#pragma unroll
    for (int off = 32; off; off >>= 1) v += __shfl_xor(v, off);
    if (lane == 0) out[wave] = v + bp[0];
}

extern "C" void kernel_launch(void* const* d_in, const int* in_sizes, int n_in,
                              void* d_out, int out_size, void* d_ws, size_t ws_size,
                              hipStream_t stream) {
    const float* x  = (const float*)d_in[0];
    const float* e0 = (const float*)d_in[1];
    const float* Wn = (const float*)d_in[2];
    const float* bn = (const float*)d_in[3];
    const float* We = (const float*)d_in[4];
    const float* be = (const float*)d_in[5];
    const float* A  = (const float*)d_in[6];
    const float* B  = (const float*)d_in[7];
    const float* C  = (const float*)d_in[8];
    const float* cb = (const float*)d_in[9];
    const float* U  = (const float*)d_in[10];
    const float* V  = (const float*)d_in[11];
    const float* Wp = (const float*)d_in[12];
    const float* bp = (const float*)d_in[13];
    const int* src  = (const int*)d_in[14];
    const int* dst  = (const int*)d_in[15];
    const int* ss   = (const int*)d_in[16];
    const int* ds   = (const int*)d_in[17];

    char* ws = (char*)d_ws;
    size_t nb = (size_t)NN * HH;
    float* h   = (float*)ws;                       // 25.6 MB
    bf16*  hAB = (bf16*)(ws + nb * 4);             // 6 × 12.8 MB
    bf16*  hV  = hAB + 6 * nb;                     // 12.8 MB
    float* num = (float*)((char*)(hV + nb));       // 25.6 MB
    float* den = num + nb;                         // 25.6 MB
    float* We0 = den + nb;                         // 128 f
    float* bb0 = We0 + 2 * HH;                     // 64 f

    encode_nodes_k<<<(NN * HH + 255) / 256, 256, 0, stream>>>(x, Wn, bn, h);
    prep_k<<<1, 64, 0, stream>>>(We, be, C, cb, We0, bb0);

    for (int l = 0; l < 3; ++l) {
        zero_k<<<2048, 256, 0, stream>>>((float4*)num, (int)(2 * nb / 4));
        node_transform_k<<<dim3(512, 3), 256, 0, stream>>>(
            h, A + (size_t)l * HH * HH, B + (size_t)l * HH * HH, V + (size_t)l * HH * HH,
            hAB + 2 * l * nb, hAB + (2 * l + 1) * nb, hV);
        if (l == 0)
            edge_chain_k<0><<<2048, 256, 0, stream>>>(e0, hAB, hV, We0, bb0, cb, C,
                                                      src, dst, num, den);
        else if (l == 1)
            edge_chain_k<1><<<2048, 256, 0, stream>>>(e0, hAB, hV, We0, bb0, cb, C,
                                                      src, dst, num, den);
        else
            edge_chain_k<2><<<2048, 256, 0, stream>>>(e0, hAB, hV, We0, bb0, cb, C,
                                                      src, dst, num, den);
        node_update_k<<<512, 256, 0, stream>>>(h, U + (size_t)l * HH * HH, num, den);
    }

    score_k<<<(int)(((size_t)NS * HH + 255) / 256), 256, 0, stream>>>(
        h, Wp, bp, ss, ds, (float*)d_out);
}

// Round 5
// 3079.189 us; speedup vs baseline: 4.8454x; 4.8454x over previous
//
#include <hip/hip_runtime.h>
#include <hip/hip_bf16.h>

using bf16 = __hip_bfloat16;

static constexpr int NN = 100000;   // nodes
static constexpr int NE = 1600000;  // message edges
static constexpr int NS = 500000;   // scored edges
static constexpr int HH = 64;       // hidden
static constexpr int SCAN_B = 1024;
static constexpr int SCAN_G = (NN + SCAN_B - 1) / SCAN_B;   // 98

__device__ __forceinline__ float b2f(bf16 v) { return __bfloat162float(v); }
__device__ __forceinline__ bf16  f2b(float v) { return __float2bfloat16(v); }
// broadcast lane k's value to all lanes via v_readlane (SGPR result, no DS pipe)
__device__ __forceinline__ float bcast(float v, int k) {
    return __uint_as_float(__builtin_amdgcn_readlane(__float_as_uint(v), k));
}

// ---------------- encode + weight prep ----------------

__global__ void encode_nodes_k(const float* __restrict__ x, const float* __restrict__ Wn,
                               const float* __restrict__ bn, float* __restrict__ h) {
    int tid = blockIdx.x * blockDim.x + threadIdx.x;
    if (tid >= NN * HH) return;
    int r = tid >> 6, j = tid & 63;
    h[tid] = fmaf(x[2 * r], Wn[j], fmaf(x[2 * r + 1], Wn[HH + j], bn[j]));
}

// Fold edge encoder into layer-0 C: We0 = We@C0 (2x64), bb0 = be@C0 + cb0
__global__ void prep_k(const float* __restrict__ We, const float* __restrict__ be,
                       const float* __restrict__ C0, const float* __restrict__ cb0,
                       float* __restrict__ We0, float* __restrict__ bb0) {
    int j = threadIdx.x;
    if (j >= HH) return;
    float s0 = 0.f, s1 = 0.f, sb = 0.f;
    for (int k = 0; k < HH; ++k) {
        float c = C0[k * HH + j];
        s0 = fmaf(We[k], c, s0);
        s1 = fmaf(We[HH + k], c, s1);
        sb = fmaf(be[k], c, sb);
    }
    We0[j] = s0; We0[HH + j] = s1; bb0[j] = sb + cb0[j];
}

// ---------------- CSR build (counting sort by dst) ----------------

__global__ void zero_int_k(int* __restrict__ p, int n) {
    int i = blockIdx.x * blockDim.x + threadIdx.x;
    if (i < n) p[i] = 0;
}

__global__ void hist_k(const int* __restrict__ dst, int* __restrict__ cnt) {
    int i = blockIdx.x * blockDim.x + threadIdx.x;
    if (i < NE) atomicAdd(&cnt[dst[i]], 1);
}

// block-exclusive scan of cnt -> rowptr, block totals -> bsum
__global__ void scan1_k(const int* __restrict__ cnt, int* __restrict__ rowptr,
                        int* __restrict__ bsum) {
    __shared__ int sm[SCAN_B];
    int t = threadIdx.x, idx = blockIdx.x * SCAN_B + t;
    int v = (idx < NN) ? cnt[idx] : 0;
    sm[t] = v;
    __syncthreads();
    for (int off = 1; off < SCAN_B; off <<= 1) {
        int add = (t >= off) ? sm[t - off] : 0;
        __syncthreads();
        sm[t] += add;
        __syncthreads();
    }
    if (idx < NN) rowptr[idx] = sm[t] - v;          // exclusive within block
    if (t == SCAN_B - 1) bsum[blockIdx.x] = sm[t];  // block total
}

__global__ void scan2_k(const int* __restrict__ bsum, int* __restrict__ bofs) {
    if (threadIdx.x == 0) {
        int acc = 0;
        for (int b = 0; b < SCAN_G; ++b) { bofs[b] = acc; acc += bsum[b]; }
    }
}

__global__ void scan3_k(int* __restrict__ rowptr, int* __restrict__ cursor,
                        const int* __restrict__ bofs) {
    int idx = blockIdx.x * SCAN_B + threadIdx.x;
    if (idx < NN) {
        int r = rowptr[idx] + bofs[blockIdx.x];
        rowptr[idx] = r;
        cursor[idx] = r;
    }
    if (idx == 0) rowptr[NN] = NE;
}

__global__ void scatter_k(const int* __restrict__ dst, int* __restrict__ cursor,
                          int* __restrict__ perm) {
    int i = blockIdx.x * blockDim.x + threadIdx.x;
    if (i < NE) {
        int p = atomicAdd(&cursor[dst[i]], 1);
        perm[p] = i;
    }
}

// ---------------- per-layer node transforms ----------------
// oA = h@A, oB = h@B, oV = h@V (bf16); wave per row, W-column in VGPRs
__global__ __launch_bounds__(256, 2)
void node_transform_k(const float* __restrict__ h, const float* __restrict__ A,
                      const float* __restrict__ B, const float* __restrict__ V,
                      bf16* __restrict__ oA, bf16* __restrict__ oB, bf16* __restrict__ oV) {
    int lane = threadIdx.x & 63;
    const float* W; bf16* out;
    if (blockIdx.y == 0)      { W = A; out = oA; }
    else if (blockIdx.y == 1) { W = B; out = oB; }
    else                      { W = V; out = oV; }
    float col[HH];
#pragma unroll
    for (int k = 0; k < HH; ++k) col[k] = W[k * HH + lane];
    int wave = blockIdx.x * (blockDim.x >> 6) + (threadIdx.x >> 6);
    int nw = gridDim.x * (blockDim.x >> 6);
    for (int r = wave; r < NN; r += nw) {
        const float* hr = h + (size_t)r * HH;
        float acc = 0.f;
#pragma unroll
        for (int k = 0; k < HH; ++k) acc = fmaf(hr[k], col[k], acc);
        out[(size_t)r * HH + lane] = f2b(acc);
    }
}

// ---------------- fused aggregate + node update, wave per dst ----------------
// tabs layout: [A0,B0,A1,B1,A2,B2] each [NN*64] bf16; e_hat chain recomputed from e0.
// Ul = U + LAYER*HH*HH (per-layer pointer!)
template <int LAYER>
__global__ __launch_bounds__(256, 2)
void aggregate_k(float* __restrict__ h, const bf16* __restrict__ tabs,
                 const bf16* __restrict__ hV,
                 const float* __restrict__ We0, const float* __restrict__ bb0,
                 const float* __restrict__ cb, const float* __restrict__ C,
                 const float* __restrict__ Ul,
                 const int* __restrict__ rowptr, const int* __restrict__ perm,
                 const int* __restrict__ src, const float2* __restrict__ e0) {
    int lane = threadIdx.x & 63;
    float c1[HH], c2[HH];
    if constexpr (LAYER >= 1) {
#pragma unroll
        for (int k = 0; k < HH; ++k) c1[k] = C[1 * HH * HH + k * HH + lane];
    }
    if constexpr (LAYER >= 2) {
#pragma unroll
        for (int k = 0; k < HH; ++k) c2[k] = C[2 * HH * HH + k * HH + lane];
    }
    float w0 = We0[lane], w1 = We0[HH + lane], b0 = bb0[lane];
    float cb1 = (LAYER >= 1) ? cb[HH + lane] : 0.f;
    float cb2 = (LAYER >= 2) ? cb[2 * HH + lane] : 0.f;
    const size_t nb = (size_t)NN * HH;

    int d = blockIdx.x * 4 + (threadIdx.x >> 6);
    if (d >= NN) return;
    d = __builtin_amdgcn_readfirstlane(d);
    int beg = rowptr[d], end = rowptr[d + 1];
    size_t drow = (size_t)d * HH + lane;

    float bB0 = b2f(tabs[nb + drow]);
    float bB1 = (LAYER >= 1) ? b2f(tabs[3 * nb + drow]) : 0.f;
    float bB2 = (LAYER >= 2) ? b2f(tabs[5 * nb + drow]) : 0.f;

    float num = 0.f, den = 0.f;
    for (int i = beg; i < end; ++i) {
        int e = __builtin_amdgcn_readfirstlane(perm[i]);
        int s = __builtin_amdgcn_readfirstlane(src[e]);
        size_t srow = (size_t)s * HH + lane;
        float2 ev = e0[e];
        float z = fmaf(ev.x, w0, fmaf(ev.y, w1, b0));
        z += b2f(tabs[srow]) + bB0;
        if constexpr (LAYER >= 1) {
            float e1 = fmaxf(z, 0.f);
            float acc = cb1 + b2f(tabs[2 * nb + srow]) + bB1;
#pragma unroll
            for (int k = 0; k < HH; ++k) acc = fmaf(bcast(e1, k), c1[k], acc);
            z = acc;
        }
        if constexpr (LAYER >= 2) {
            float e2 = fmaxf(z, 0.f);
            float acc = cb2 + b2f(tabs[4 * nb + srow]) + bB2;
#pragma unroll
            for (int k = 0; k < HH; ++k) acc = fmaf(bcast(e2, k), c2[k], acc);
            z = acc;
        }
        float sig = 1.f / (1.f + __expf(-z));
        num = fmaf(sig, b2f(hV[srow]), num);
        den += sig;
    }

    // fused: h[d] = relu(h[d]@U_l + num/(den+1e-6))
    float hd = h[drow];
    float hu = 0.f;
#pragma unroll
    for (int k = 0; k < HH; ++k) hu = fmaf(bcast(hd, k), Ul[k * HH + lane], hu);
    h[drow] = fmaxf(hu + num / (den + 1e-6f), 0.f);
}

// ---------------- scoring ----------------
__global__ void score_k(const float* __restrict__ h, const float* __restrict__ Wp,
                        const float* __restrict__ bp, const int* __restrict__ ss,
                        const int* __restrict__ ds, float* __restrict__ out) {
    int lane = threadIdx.x & 63;
    int wave = (blockIdx.x * blockDim.x + threadIdx.x) >> 6;
    if (wave >= NS) return;
    int s = ss[wave], d = ds[wave];
    float v = fmaf(h[(size_t)s * HH + lane], Wp[lane],
                   h[(size_t)d * HH + lane] * Wp[HH + lane]);
#pragma unroll
    for (int off = 32; off; off >>= 1) v += __shfl_xor(v, off);
    if (lane == 0) out[wave] = v + bp[0];
}

extern "C" void kernel_launch(void* const* d_in, const int* in_sizes, int n_in,
                              void* d_out, int out_size, void* d_ws, size_t ws_size,
                              hipStream_t stream) {
    const float* x  = (const float*)d_in[0];
    const float* e0 = (const float*)d_in[1];
    const float* Wn = (const float*)d_in[2];
    const float* bn = (const float*)d_in[3];
    const float* We = (const float*)d_in[4];
    const float* be = (const float*)d_in[5];
    const float* A  = (const float*)d_in[6];
    const float* B  = (const float*)d_in[7];
    const float* C  = (const float*)d_in[8];
    const float* cb = (const float*)d_in[9];
    const float* U  = (const float*)d_in[10];
    const float* V  = (const float*)d_in[11];
    const float* Wp = (const float*)d_in[12];
    const float* bp = (const float*)d_in[13];
    const int* src  = (const int*)d_in[14];
    const int* dst  = (const int*)d_in[15];
    const int* ss   = (const int*)d_in[16];
    const int* ds   = (const int*)d_in[17];

    char* ws = (char*)d_ws;
    size_t nb = (size_t)NN * HH;
    float* h      = (float*)ws;                    // 25.6 MB
    bf16*  tabs   = (bf16*)(ws + nb * 4);          // 6 x 12.8 MB
    bf16*  hV     = tabs + 6 * nb;                 // 12.8 MB
    int*   perm   = (int*)(hV + nb);               // 6.4 MB
    int*   cnt    = perm + NE;                     // 0.4 MB
    int*   rowptr = cnt + NN;                      // 0.4 MB
    int*   cursor = rowptr + (NN + 1);             // 0.4 MB
    int*   bsum   = cursor + NN;
    int*   bofs   = bsum + SCAN_G;
    float* We0    = (float*)(bofs + SCAN_G);
    float* bb0    = We0 + 2 * HH;

    encode_nodes_k<<<(NN * HH + 255) / 256, 256, 0, stream>>>(x, Wn, bn, h);
    prep_k<<<1, 64, 0, stream>>>(We, be, C, cb, We0, bb0);

    // CSR build (once per call, reused by all 3 layers)
    zero_int_k<<<(NN + 255) / 256, 256, 0, stream>>>(cnt, NN);
    hist_k<<<(NE + 255) / 256, 256, 0, stream>>>(dst, cnt);
    scan1_k<<<SCAN_G, SCAN_B, 0, stream>>>(cnt, rowptr, bsum);
    scan2_k<<<1, 64, 0, stream>>>(bsum, bofs);
    scan3_k<<<SCAN_G, SCAN_B, 0, stream>>>(rowptr, cursor, bofs);
    scatter_k<<<(NE + 255) / 256, 256, 0, stream>>>(dst, cursor, perm);

    for (int l = 0; l < 3; ++l) {
        node_transform_k<<<dim3(512, 3), 256, 0, stream>>>(
            h, A + (size_t)l * HH * HH, B + (size_t)l * HH * HH, V + (size_t)l * HH * HH,
            tabs + 2 * (size_t)l * nb, tabs + (2 * (size_t)l + 1) * nb, hV);
        const float* Ul = U + (size_t)l * HH * HH;
        if (l == 0)
            aggregate_k<0><<<(NN + 3) / 4, 256, 0, stream>>>(
                h, tabs, hV, We0, bb0, cb, C, Ul, rowptr, perm, src, (const float2*)e0);
        else if (l == 1)
            aggregate_k<1><<<(NN + 3) / 4, 256, 0, stream>>>(
                h, tabs, hV, We0, bb0, cb, C, Ul, rowptr, perm, src, (const float2*)e0);
        else
            aggregate_k<2><<<(NN + 3) / 4, 256, 0, stream>>>(
                h, tabs, hV, We0, bb0, cb, C, Ul, rowptr, perm, src, (const float2*)e0);
    }

    score_k<<<(int)(((size_t)NS * HH + 255) / 256), 256, 0, stream>>>(
        h, Wp, bp, ss, ds, (float*)d_out);
}